// Round 8
// baseline (356.901 us; speedup 1.0000x reference)
//
#include <hip/hip_runtime.h>
#include <math.h>

#define NEG_SLOPE 0.2f
#define BCAP 4096    // bucket capacity for k_build LDS (mean 2176, 41 sigma headroom)
#define TILE 4096    // edges per block in hist/scatter passes

using short8 = __attribute__((ext_vector_type(8))) short;
using f32x4 = __attribute__((ext_vector_type(4))) float;

__device__ __forceinline__ float leaky(float x) { return x > 0.f ? x : NEG_SLOPE * x; }

__device__ __forceinline__ float wmax64(float v) {
#pragma unroll
  for (int off = 32; off; off >>= 1) v = fmaxf(v, __shfl_xor(v, off));
  return v;
}
__device__ __forceinline__ float wsum64(float v) {
#pragma unroll
  for (int off = 32; off; off >>= 1) v += __shfl_xor(v, off);
  return v;
}

// fp32 -> bf16 round-to-nearest-even
__device__ __forceinline__ unsigned short f2bf(float f) {
  union { float f; unsigned u; } x; x.f = f;
  unsigned r = x.u + 0x7fff + ((x.u >> 16) & 1);
  return (unsigned short)(r >> 16);
}
__device__ __forceinline__ float bf2f(unsigned short h) {
  union { unsigned u; float f; } x; x.u = (unsigned)h << 16;
  return x.f;
}

// ---------------- CSR pass 1 + W split (fused, disjoint block ranges) ----------------
__global__ __launch_bounds__(256) void k_hist_wsplit(
    const int* __restrict__ dst, int* __restrict__ blkhist, int E, int nb, int nblk,
    const float* __restrict__ W0, const float* __restrict__ W1,
    unsigned short* __restrict__ Wth0, unsigned short* __restrict__ Wtl0,
    unsigned short* __restrict__ Wth1, unsigned short* __restrict__ Wtl1) {
  __shared__ int h[512];
  if (blockIdx.x < 128) {
    int i = blockIdx.x * 256 + threadIdx.x;  // 32768 total
    int j = i & 16383;
    int k = j >> 7, n = j & 127;
    const float* W = (i < 16384) ? W0 : W1;
    float v = W[j];
    unsigned short hi = f2bf(v);
    unsigned short lo = f2bf(v - bf2f(hi));
    if (i < 16384) {
      Wth0[n * 128 + k] = hi;
      Wtl0[n * 128 + k] = lo;
    } else {
      Wth1[n * 128 + k] = hi;
      Wtl1[n * 128 + k] = lo;
    }
    return;
  }
  int blk = blockIdx.x - 128;
  for (int i = threadIdx.x; i < nb; i += 256) h[i] = 0;
  __syncthreads();
  int t0 = blk * TILE;
  int end = t0 + TILE < E ? t0 + TILE : E;
  for (int i = t0 + threadIdx.x; i < end; i += 256) atomicAdd(&h[dst[i] >> 7], 1);
  __syncthreads();
  for (int i = threadIdx.x; i < nb; i += 256) blkhist[(size_t)i * nblk + blk] = h[i];
}

// ---------------- pass 2: per-bucket scan over blocks -> block offsets + totals ----------------
__global__ __launch_bounds__(256) void k_bofs(int* __restrict__ blkhist,
                                              int* __restrict__ btot, int nblk) {
  __shared__ int sd[256];
  int b = blockIdx.x, t = threadIdx.x;
  int v = (t < nblk) ? blkhist[(size_t)b * nblk + t] : 0;
  sd[t] = v;
  __syncthreads();
  for (int off = 1; off < 256; off <<= 1) {
    int add = (t >= off) ? sd[t - off] : 0;
    __syncthreads();
    sd[t] += add;
    __syncthreads();
  }
  if (t < nblk) blkhist[(size_t)b * nblk + t] = sd[t] - v;  // exclusive
  if (t == 255) btot[b] = sd[255];
}

// ---------------- pass 3: scatter into bucket-sorted store (local bscan) ----------------
__global__ __launch_bounds__(256) void k_scatter2(
    const int* __restrict__ src, const int* __restrict__ dst,
    const int* __restrict__ blkhist, const int* __restrict__ btot,
    int2* __restrict__ bstore, int E, int nb, int nblk) {
  __shared__ int sd[256];
  __shared__ int bb[512];
  __shared__ int cur[512];
  int t = threadIdx.x, blk = blockIdx.x;
  int v0 = (2 * t < nb) ? btot[2 * t] : 0;
  int v1 = (2 * t + 1 < nb) ? btot[2 * t + 1] : 0;
  int s = v0 + v1;
  sd[t] = s;
  __syncthreads();
  for (int off = 1; off < 256; off <<= 1) {
    int add = (t >= off) ? sd[t - off] : 0;
    __syncthreads();
    sd[t] += add;
    __syncthreads();
  }
  int run = sd[t] - s;
  if (2 * t < nb) bb[2 * t] = run;
  if (2 * t + 1 < nb) bb[2 * t + 1] = run + v0;
  __syncthreads();
  for (int i = t; i < nb; i += 256)
    cur[i] = bb[i] + blkhist[(size_t)i * nblk + blk];
  __syncthreads();
  int t0 = blk * TILE;
  int end = t0 + TILE < E ? t0 + TILE : E;
  for (int i = t0 + t; i < end; i += 256) {
    int d = dst[i];
    int pos = atomicAdd(&cur[d >> 7], 1);  // LDS atomic, block-local
    bstore[pos] = make_int2(src[i], d);
  }
}

// ---------------- pass 4: per-bucket local CSR (one block per 128-node bucket) ----------------
__global__ __launch_bounds__(256) void k_build(
    const int2* __restrict__ bstore, const int* __restrict__ btot,
    int* __restrict__ ssrc, int* __restrict__ deg, int* __restrict__ rstart, int N) {
  __shared__ int ls[BCAP];
  __shared__ unsigned char lloc[BCAP];
  __shared__ int lout[BCAP];
  __shared__ int hist[128];
  __shared__ int sc[128];
  __shared__ int lcur[128];
  __shared__ int red[256];
  int b = blockIdx.x;
  int t = threadIdx.x;
  int pacc = 0;
  for (int j = t; j < b; j += 256) pacc += btot[j];
  red[t] = pacc;
  __syncthreads();
  for (int off = 128; off; off >>= 1) {
    if (t < off) red[t] += red[t + off];
    __syncthreads();
  }
  int base = red[0];
  int cnt = btot[b];
  if (cnt > BCAP) cnt = BCAP;
  int nlo = b << 7;
  if (t < 128) { hist[t] = 0; lcur[t] = 0; }
  __syncthreads();
  for (int i = t; i < cnt; i += 256) {
    int2 e = bstore[base + i];
    int loc = e.y - nlo;
    ls[i] = e.x;
    lloc[i] = (unsigned char)loc;
    atomicAdd(&hist[loc], 1);
  }
  __syncthreads();
  int hv = (t < 128) ? hist[t] : 0;
  if (t < 128) sc[t] = hv;
  __syncthreads();
  for (int off = 1; off < 128; off <<= 1) {
    int add = (t < 128 && t >= off) ? sc[t - off] : 0;
    __syncthreads();
    if (t < 128) sc[t] += add;
    __syncthreads();
  }
  int lstart = (t < 128) ? sc[t] - hv : 0;  // exclusive
  if (t < 128) sc[t] = lstart;
  if (t < 128 && nlo + t < N) {
    deg[nlo + t] = hv;
    rstart[nlo + t] = base + lstart;
  }
  __syncthreads();
  for (int i = t; i < cnt; i += 256) {
    int loc = lloc[i];
    int slot = sc[loc] + atomicAdd(&lcur[loc], 1);
    lout[slot] = ls[i];
  }
  __syncthreads();
  for (int i = t; i < cnt; i += 256) ssrc[base + i] = lout[i];
}

// ---------------- split-bf16 3-pass MFMA GEMM + fused logits ----------------
#define PA 136  // Ah/Al row pitch (bf16): +8 pad
#define PW 40   // Wh/Wl row pitch
__global__ __launch_bounds__(256, 2) void k_gemm_mfma(
    const float* __restrict__ A, const unsigned short* __restrict__ Wth,
    const unsigned short* __restrict__ Wtl, const float* __restrict__ a_src,
    const float* __restrict__ a_dst, unsigned short* __restrict__ xph,
    float* __restrict__ als, float* __restrict__ ald, int nrows) {
  __shared__ unsigned short Ah[64 * PA];
  __shared__ unsigned short Al[64 * PA];
  __shared__ unsigned short Wh[128 * PW];
  __shared__ unsigned short Wl[128 * PW];
  int t = threadIdx.x;
  int row0 = blockIdx.x * 64;

  const float4* A4 = (const float4*)A;
#pragma unroll
  for (int p = 0; p < 8; ++p) {
    int idx = t + p * 256;  // 2048 float4 = 64 rows x 32
    int row = idx >> 5, k4 = idx & 31;
    int gr = row0 + row;
    float4 v = make_float4(0.f, 0.f, 0.f, 0.f);
    if (gr < nrows) v = A4[(size_t)gr * 32 + k4];
    ushort4 hi, lo;
    hi.x = f2bf(v.x); lo.x = f2bf(v.x - bf2f(hi.x));
    hi.y = f2bf(v.y); lo.y = f2bf(v.y - bf2f(hi.y));
    hi.z = f2bf(v.z); lo.z = f2bf(v.z - bf2f(hi.z));
    hi.w = f2bf(v.w); lo.w = f2bf(v.w - bf2f(hi.w));
    *(ushort4*)&Ah[row * PA + k4 * 4] = hi;
    *(ushort4*)&Al[row * PA + k4 * 4] = lo;
  }

  int lane = t & 63, wv = t >> 6;
  int wr = wv >> 1, wc = wv & 1;
  int ml = lane & 15, q = lane >> 4;
  f32x4 acc[2][4] = {};

  for (int kb = 0; kb < 4; ++kb) {
    __syncthreads();
    int k0 = kb * 32;
#pragma unroll
    for (int p = 0; p < 8; ++p) {
      int idx = t + p * 256;  // 2048 u32 = 128 n x 16 k-pairs
      int n = idx >> 4, kp = idx & 15;
      *(unsigned*)&Wh[n * PW + kp * 2] =
          *(const unsigned*)(Wth + (size_t)n * 128 + k0 + kp * 2);
      *(unsigned*)&Wl[n * PW + kp * 2] =
          *(const unsigned*)(Wtl + (size_t)n * 128 + k0 + kp * 2);
    }
    __syncthreads();
    int kf = k0 + q * 8;
    short8 a_h0 = *(const short8*)&Ah[(wr * 32 + ml) * PA + kf];
    short8 a_h1 = *(const short8*)&Ah[(wr * 32 + 16 + ml) * PA + kf];
    short8 a_l0 = *(const short8*)&Al[(wr * 32 + ml) * PA + kf];
    short8 a_l1 = *(const short8*)&Al[(wr * 32 + 16 + ml) * PA + kf];
#pragma unroll
    for (int ct = 0; ct < 4; ++ct) {
      int nb = (wc * 64 + ct * 16 + ml) * PW + q * 8;
      short8 b_h = *(const short8*)&Wh[nb];
      short8 b_l = *(const short8*)&Wl[nb];
      acc[0][ct] = __builtin_amdgcn_mfma_f32_16x16x32_bf16(a_h0, b_h, acc[0][ct], 0, 0, 0);
      acc[0][ct] = __builtin_amdgcn_mfma_f32_16x16x32_bf16(a_h0, b_l, acc[0][ct], 0, 0, 0);
      acc[0][ct] = __builtin_amdgcn_mfma_f32_16x16x32_bf16(a_l0, b_h, acc[0][ct], 0, 0, 0);
      acc[1][ct] = __builtin_amdgcn_mfma_f32_16x16x32_bf16(a_h1, b_h, acc[1][ct], 0, 0, 0);
      acc[1][ct] = __builtin_amdgcn_mfma_f32_16x16x32_bf16(a_h1, b_l, acc[1][ct], 0, 0, 0);
      acc[1][ct] = __builtin_amdgcn_mfma_f32_16x16x32_bf16(a_l1, b_h, acc[1][ct], 0, 0, 0);
    }
  }

  float asr[4], adr[4];
#pragma unroll
  for (int ct = 0; ct < 4; ++ct) {
    int col = (wc * 2 + (ct >> 1)) * 32 + (ct & 1) * 16 + ml;
    asr[ct] = a_src[col];
    adr[ct] = a_dst[col];
  }

#pragma unroll
  for (int rt = 0; rt < 2; ++rt) {
#pragma unroll
    for (int r = 0; r < 4; ++r) {
      int gr = row0 + wr * 32 + rt * 16 + q * 4 + r;
      bool valid = gr < nrows;
      if (valid) {
#pragma unroll
        for (int ct = 0; ct < 4; ++ct) {
          int gc = wc * 64 + ct * 16 + ml;
          xph[(size_t)gr * 128 + gc] = f2bf(acc[rt][ct][r]);
        }
      }
      float p0 = acc[rt][0][r] * asr[0] + acc[rt][1][r] * asr[1];
      float p1 = acc[rt][2][r] * asr[2] + acc[rt][3][r] * asr[3];
      float d0 = acc[rt][0][r] * adr[0] + acc[rt][1][r] * adr[1];
      float d1 = acc[rt][2][r] * adr[2] + acc[rt][3][r] * adr[3];
#pragma unroll
      for (int off = 1; off <= 8; off <<= 1) {
        p0 += __shfl_xor(p0, off); p1 += __shfl_xor(p1, off);
        d0 += __shfl_xor(d0, off); d1 += __shfl_xor(d1, off);
      }
      if (ml == 0 && valid) {
        als[(size_t)gr * 4 + wc * 2] = p0;
        als[(size_t)gr * 4 + wc * 2 + 1] = p1;
        ald[(size_t)gr * 4 + wc * 2] = d0;
        ald[(size_t)gr * 4 + wc * 2 + 1] = d1;
      }
    }
  }
}

// ---------------- per-(node,head) softmax + aggregation ----------------
// One wave per (node, head). Head is the SLOWEST block index: concurrently
// resident blocks share one head -> xph working set = one 64-B line per src
// row = 3.2 MB, fits a 4-MB per-XCD L2 (dispatch-order locality heuristic).
// Phase B: 8 edge-slots x 8 chan-groups; each edge = 8 lanes x 8 B = 1 line.
__global__ __launch_bounds__(256) void k_aggregate(
    const unsigned short* __restrict__ xph, const float* __restrict__ als,
    const float* __restrict__ ald, const int* __restrict__ rstart,
    const int* __restrict__ deg, const int* __restrict__ ssrc,
    const float* __restrict__ bias, float* __restrict__ out, int N, int nbk) {
  __shared__ float pbuf[4][128];
  __shared__ int snbuf[4][128];
  int wv = threadIdx.x >> 6;
  int lane = threadIdx.x & 63;
  int h = blockIdx.x / nbk;        // head-major
  int n = (blockIdx.x % nbk) * 4 + wv;
  if (n >= N) return;
  int start = rstart[n];
  int d = deg[n];
  float adh = ald[(size_t)n * 4 + h];

  // ---- phase A: this head's softmax over incoming edges ----
  float s;
  if (d <= 64) {
    bool valid = lane < d;
    int sn = valid ? ssrc[start + lane] : 0;
    snbuf[wv][lane] = sn;
    float av = als[(size_t)sn * 4 + h];
    float L = valid ? leaky(av + adh) : -INFINITY;
    float m = wmax64(L);
    float p = __expf(L - m);  // invalid lanes: exp(-inf)=0
    pbuf[wv][lane] = p;
    s = wsum64(p);
  } else {  // rare fallback (graph max deg ~45)
    float m = -INFINITY;
    for (int base = 0; base < d; base += 64) {
      int i = base + lane;
      bool valid = i < d;
      int sn = valid ? ssrc[start + i] : 0;
      if (valid) snbuf[wv][i] = sn;
      float av = als[(size_t)sn * 4 + h];
      float L = valid ? leaky(av + adh) : -INFINITY;
      if (valid) pbuf[wv][i] = L;
      m = fmaxf(m, wmax64(L));
    }
    s = 0.f;
    for (int base = 0; base < d; base += 64) {
      int i = base + lane;
      bool valid = i < d;
      float L = valid ? pbuf[wv][i] : -INFINITY;
      float p = __expf(L - m);
      if (valid) pbuf[wv][i] = p;
      s += wsum64(p);
    }
  }

  // ---- phase B: gather this head's 64-B line per edge ----
  int es = lane >> 3;   // edge slot 0..7
  int cg = lane & 7;    // channel group: 4 channels
  int c0 = h * 32 + cg * 4;
  float a0 = 0.f, a1 = 0.f, a2 = 0.f, a3 = 0.f;
  for (int t = es; t < d; t += 8) {
    int sn = snbuf[wv][t];
    float p = pbuf[wv][t];
    uint2 rv = *(const uint2*)(xph + (size_t)sn * 128 + c0);
    a0 += p * __uint_as_float(rv.x << 16);
    a1 += p * __uint_as_float(rv.x & 0xffff0000u);
    a2 += p * __uint_as_float(rv.y << 16);
    a3 += p * __uint_as_float(rv.y & 0xffff0000u);
  }
#pragma unroll
  for (int off = 8; off <= 32; off <<= 1) {
    a0 += __shfl_xor(a0, off); a1 += __shfl_xor(a1, off);
    a2 += __shfl_xor(a2, off); a3 += __shfl_xor(a3, off);
  }
  if (es == 0) {
    float inv = 1.f / (s + 1e-16f);
    float4 bv = *(const float4*)(bias + c0);
    float4 o;
    o.x = fmaxf(a0 * inv + bv.x, 0.f);
    o.y = fmaxf(a1 * inv + bv.y, 0.f);
    o.z = fmaxf(a2 * inv + bv.z, 0.f);
    o.w = fmaxf(a3 * inv + bv.w, 0.f);
    *(float4*)(out + (size_t)n * 128 + c0) = o;
  }
}

extern "C" void kernel_launch(void* const* d_in, const int* in_sizes, int n_in,
                              void* d_out, int out_size, void* d_ws, size_t ws_size,
                              hipStream_t stream) {
  const float* x   = (const float*)d_in[0];
  const int*   src = (const int*)d_in[1];
  const int*   dst = (const int*)d_in[2];
  const float* W0  = (const float*)d_in[3];
  const float* as0 = (const float*)d_in[4];
  const float* ad0 = (const float*)d_in[5];
  const float* b0  = (const float*)d_in[6];
  const float* W1  = (const float*)d_in[7];
  const float* as1 = (const float*)d_in[8];
  const float* ad1 = (const float*)d_in[9];
  const float* b1  = (const float*)d_in[10];
  float* out = (float*)d_out;

  int N = in_sizes[0] / 128;
  int E = in_sizes[1];
  int NB = (N + 127) >> 7;          // buckets of 128 nodes (391)
  int NBLK = (E + TILE - 1) / TILE; // hist/scatter blocks (208, must be <=256)

  char* w = (char*)d_ws;
  auto alloc = [&](size_t bytes) {
    char* p = w;
    w += (bytes + 255) & ~(size_t)255;
    return p;
  };
  int* deg     = (int*)alloc((size_t)N * 4);
  int* rstart  = (int*)alloc((size_t)N * 4);
  int* blkhist = (int*)alloc((size_t)NB * NBLK * 4);
  int* btot    = (int*)alloc((size_t)NB * 4);
  int2* bstore = (int2*)alloc((size_t)E * 8);
  int* ssrc    = (int*)alloc((size_t)E * 4);
  unsigned short* xph = (unsigned short*)alloc((size_t)N * 128 * 2);
  float* hbuf  = (float*)alloc((size_t)N * 128 * 4);
  float* als   = (float*)alloc((size_t)N * 4 * 4);
  float* ald   = (float*)alloc((size_t)N * 4 * 4);
  unsigned short* Wth0 = (unsigned short*)alloc(16384 * 2);
  unsigned short* Wtl0 = (unsigned short*)alloc(16384 * 2);
  unsigned short* Wth1 = (unsigned short*)alloc(16384 * 2);
  unsigned short* Wtl1 = (unsigned short*)alloc(16384 * 2);

  // CSR build (fused with W split) -> per-bucket offsets -> scatter -> local CSR
  k_hist_wsplit<<<128 + NBLK, 256, 0, stream>>>(dst, blkhist, E, NB, NBLK,
                                                W0, W1, Wth0, Wtl0, Wth1, Wtl1);
  k_bofs<<<NB, 256, 0, stream>>>(blkhist, btot, NBLK);
  k_scatter2<<<NBLK, 256, 0, stream>>>(src, dst, blkhist, btot, bstore, E, NB, NBLK);
  k_build<<<NB, 256, 0, stream>>>(bstore, btot, ssrc, deg, rstart, N);

  int gb = (N + 63) / 64;
  int nbk = (N + 3) / 4;  // node-chunks per head; grid = 4 heads x nbk, head-major
  // ---- layer 1 ----
  k_gemm_mfma<<<gb, 256, 0, stream>>>(x, Wth0, Wtl0, as0, ad0, xph, als, ald, N);
  k_aggregate<<<4 * nbk, 256, 0, stream>>>(xph, als, ald, rstart, deg, ssrc, b0, hbuf, N, nbk);

  // ---- layer 2 ----
  k_gemm_mfma<<<gb, 256, 0, stream>>>(hbuf, Wth1, Wtl1, as1, ad1, xph, als, ald, N);
  k_aggregate<<<4 * nbk, 256, 0, stream>>>(xph, als, ald, rstart, deg, ssrc, b1, out, N, nbk);
}

// Round 9
// 247.118 us; speedup vs baseline: 1.4443x; 1.4443x over previous
//
#include <hip/hip_runtime.h>
#include <math.h>

#define NEG_SLOPE 0.2f
#define BCAP 4096    // bucket capacity for k_build LDS (mean 2176, 41 sigma headroom)
#define TILE 8192    // edges per block in hist/scatter passes

using short8 = __attribute__((ext_vector_type(8))) short;
using f32x4 = __attribute__((ext_vector_type(4))) float;

__device__ __forceinline__ float leaky(float x) { return x > 0.f ? x : NEG_SLOPE * x; }

__device__ __forceinline__ float wmax64(float v) {
#pragma unroll
  for (int off = 32; off; off >>= 1) v = fmaxf(v, __shfl_xor(v, off));
  return v;
}
__device__ __forceinline__ float wsum64(float v) {
#pragma unroll
  for (int off = 32; off; off >>= 1) v += __shfl_xor(v, off);
  return v;
}

// fp32 -> bf16 round-to-nearest-even
__device__ __forceinline__ unsigned short f2bf(float f) {
  union { float f; unsigned u; } x; x.f = f;
  unsigned r = x.u + 0x7fff + ((x.u >> 16) & 1);
  return (unsigned short)(r >> 16);
}
__device__ __forceinline__ float bf2f(unsigned short h) {
  union { unsigned u; float f; } x; x.u = (unsigned)h << 16;
  return x.f;
}

__device__ __forceinline__ void acc8(float* a, float p, uint4 rv) {
  a[0] += p * __uint_as_float(rv.x << 16);
  a[1] += p * __uint_as_float(rv.x & 0xffff0000u);
  a[2] += p * __uint_as_float(rv.y << 16);
  a[3] += p * __uint_as_float(rv.y & 0xffff0000u);
  a[4] += p * __uint_as_float(rv.z << 16);
  a[5] += p * __uint_as_float(rv.z & 0xffff0000u);
  a[6] += p * __uint_as_float(rv.w << 16);
  a[7] += p * __uint_as_float(rv.w & 0xffff0000u);
}

// ---------------- split-bf16 3-pass MFMA GEMM + fused logits (device body) ----------------
#define PA 136  // Ah/Al row pitch (bf16): +8 pad
#define PW 40   // Wh/Wl row pitch
__device__ void gemm_body(
    const float* __restrict__ A, const unsigned short* __restrict__ Wth,
    const unsigned short* __restrict__ Wtl, const float* __restrict__ a_src,
    const float* __restrict__ a_dst, unsigned short* __restrict__ xph,
    float* __restrict__ als, float* __restrict__ ald, int nrows, int blk) {
  __shared__ unsigned short Ah[64 * PA];
  __shared__ unsigned short Al[64 * PA];
  __shared__ unsigned short Wh[128 * PW];
  __shared__ unsigned short Wl[128 * PW];
  int t = threadIdx.x;
  int row0 = blk * 64;

  const float4* A4 = (const float4*)A;
#pragma unroll
  for (int p = 0; p < 8; ++p) {
    int idx = t + p * 256;  // 2048 float4 = 64 rows x 32
    int row = idx >> 5, k4 = idx & 31;
    int gr = row0 + row;
    float4 v = make_float4(0.f, 0.f, 0.f, 0.f);
    if (gr < nrows) v = A4[(size_t)gr * 32 + k4];
    ushort4 hi, lo;
    hi.x = f2bf(v.x); lo.x = f2bf(v.x - bf2f(hi.x));
    hi.y = f2bf(v.y); lo.y = f2bf(v.y - bf2f(hi.y));
    hi.z = f2bf(v.z); lo.z = f2bf(v.z - bf2f(hi.z));
    hi.w = f2bf(v.w); lo.w = f2bf(v.w - bf2f(hi.w));
    *(ushort4*)&Ah[row * PA + k4 * 4] = hi;
    *(ushort4*)&Al[row * PA + k4 * 4] = lo;
  }

  int lane = t & 63, wv = t >> 6;
  int wr = wv >> 1, wc = wv & 1;
  int ml = lane & 15, q = lane >> 4;
  f32x4 acc[2][4] = {};

  for (int kb = 0; kb < 4; ++kb) {
    __syncthreads();
    int k0 = kb * 32;
#pragma unroll
    for (int p = 0; p < 8; ++p) {
      int idx = t + p * 256;  // 2048 u32 = 128 n x 16 k-pairs
      int n = idx >> 4, kp = idx & 15;
      *(unsigned*)&Wh[n * PW + kp * 2] =
          *(const unsigned*)(Wth + (size_t)n * 128 + k0 + kp * 2);
      *(unsigned*)&Wl[n * PW + kp * 2] =
          *(const unsigned*)(Wtl + (size_t)n * 128 + k0 + kp * 2);
    }
    __syncthreads();
    int kf = k0 + q * 8;
    short8 a_h0 = *(const short8*)&Ah[(wr * 32 + ml) * PA + kf];
    short8 a_h1 = *(const short8*)&Ah[(wr * 32 + 16 + ml) * PA + kf];
    short8 a_l0 = *(const short8*)&Al[(wr * 32 + ml) * PA + kf];
    short8 a_l1 = *(const short8*)&Al[(wr * 32 + 16 + ml) * PA + kf];
#pragma unroll
    for (int ct = 0; ct < 4; ++ct) {
      int nb = (wc * 64 + ct * 16 + ml) * PW + q * 8;
      short8 b_h = *(const short8*)&Wh[nb];
      short8 b_l = *(const short8*)&Wl[nb];
      acc[0][ct] = __builtin_amdgcn_mfma_f32_16x16x32_bf16(a_h0, b_h, acc[0][ct], 0, 0, 0);
      acc[0][ct] = __builtin_amdgcn_mfma_f32_16x16x32_bf16(a_h0, b_l, acc[0][ct], 0, 0, 0);
      acc[0][ct] = __builtin_amdgcn_mfma_f32_16x16x32_bf16(a_l0, b_h, acc[0][ct], 0, 0, 0);
      acc[1][ct] = __builtin_amdgcn_mfma_f32_16x16x32_bf16(a_h1, b_h, acc[1][ct], 0, 0, 0);
      acc[1][ct] = __builtin_amdgcn_mfma_f32_16x16x32_bf16(a_h1, b_l, acc[1][ct], 0, 0, 0);
      acc[1][ct] = __builtin_amdgcn_mfma_f32_16x16x32_bf16(a_l1, b_h, acc[1][ct], 0, 0, 0);
    }
  }

  float asr[4], adr[4];
#pragma unroll
  for (int ct = 0; ct < 4; ++ct) {
    int col = (wc * 2 + (ct >> 1)) * 32 + (ct & 1) * 16 + ml;
    asr[ct] = a_src[col];
    adr[ct] = a_dst[col];
  }

#pragma unroll
  for (int rt = 0; rt < 2; ++rt) {
#pragma unroll
    for (int r = 0; r < 4; ++r) {
      int gr = row0 + wr * 32 + rt * 16 + q * 4 + r;
      bool valid = gr < nrows;
      if (valid) {
#pragma unroll
        for (int ct = 0; ct < 4; ++ct) {
          int gc = wc * 64 + ct * 16 + ml;
          xph[(size_t)gr * 128 + gc] = f2bf(acc[rt][ct][r]);
        }
      }
      float p0 = acc[rt][0][r] * asr[0] + acc[rt][1][r] * asr[1];
      float p1 = acc[rt][2][r] * asr[2] + acc[rt][3][r] * asr[3];
      float d0 = acc[rt][0][r] * adr[0] + acc[rt][1][r] * adr[1];
      float d1 = acc[rt][2][r] * adr[2] + acc[rt][3][r] * adr[3];
#pragma unroll
      for (int off = 1; off <= 8; off <<= 1) {
        p0 += __shfl_xor(p0, off); p1 += __shfl_xor(p1, off);
        d0 += __shfl_xor(d0, off); d1 += __shfl_xor(d1, off);
      }
      if (ml == 0 && valid) {
        als[(size_t)gr * 4 + wc * 2] = p0;
        als[(size_t)gr * 4 + wc * 2 + 1] = p1;
        ald[(size_t)gr * 4 + wc * 2] = d0;
        ald[(size_t)gr * 4 + wc * 2 + 1] = d1;
      }
    }
  }
}

// ---------------- CSR pass 1 + W split (fused, disjoint block ranges) ----------------
__global__ __launch_bounds__(256) void k_hist_wsplit(
    const int* __restrict__ dst, int* __restrict__ blkhist, int E, int nb, int nblk,
    const float* __restrict__ W0, const float* __restrict__ W1,
    unsigned short* __restrict__ Wth0, unsigned short* __restrict__ Wtl0,
    unsigned short* __restrict__ Wth1, unsigned short* __restrict__ Wtl1) {
  __shared__ int h[512];
  if (blockIdx.x < 128) {
    int i = blockIdx.x * 256 + threadIdx.x;  // 32768 total
    int j = i & 16383;
    int k = j >> 7, n = j & 127;
    const float* W = (i < 16384) ? W0 : W1;
    float v = W[j];
    unsigned short hi = f2bf(v);
    unsigned short lo = f2bf(v - bf2f(hi));
    if (i < 16384) {
      Wth0[n * 128 + k] = hi;
      Wtl0[n * 128 + k] = lo;
    } else {
      Wth1[n * 128 + k] = hi;
      Wtl1[n * 128 + k] = lo;
    }
    return;
  }
  int blk = blockIdx.x - 128;
  for (int i = threadIdx.x; i < nb; i += 256) h[i] = 0;
  __syncthreads();
  int t0 = blk * TILE;
  int end = t0 + TILE < E ? t0 + TILE : E;
  for (int i = t0 + threadIdx.x; i < end; i += 256) atomicAdd(&h[dst[i] >> 7], 1);
  __syncthreads();
  for (int i = threadIdx.x; i < nb; i += 256) blkhist[(size_t)i * nblk + blk] = h[i];
}

// ---------------- pass 2: per-bucket scan over blocks -> block offsets + totals ----------------
__global__ __launch_bounds__(256) void k_bofs(int* __restrict__ blkhist,
                                              int* __restrict__ btot, int nblk) {
  __shared__ int sd[256];
  int b = blockIdx.x, t = threadIdx.x;
  int v = (t < nblk) ? blkhist[(size_t)b * nblk + t] : 0;
  sd[t] = v;
  __syncthreads();
  for (int off = 1; off < 256; off <<= 1) {
    int add = (t >= off) ? sd[t - off] : 0;
    __syncthreads();
    sd[t] += add;
    __syncthreads();
  }
  if (t < nblk) blkhist[(size_t)b * nblk + t] = sd[t] - v;  // exclusive
  if (t == 255) btot[b] = sd[255];
}

// ---------------- pass 3 + layer-1 GEMM (fused, disjoint block ranges) ----------------
// Blocks [0,nblk): scatter edges into bucket-sorted packed store (LDS cursors,
// bucket bases from local scan of btot). Blocks [nblk,...): layer-1 MFMA GEMM
// (independent of the CSR chain; only needs k_hist_wsplit's Wth0/Wtl0).
// Packed entry: (dst&127)<<16 | src  — requires N < 65536.
__global__ __launch_bounds__(256, 2) void k_scatter2_gemm(
    const int* __restrict__ src, const int* __restrict__ dst,
    const int* __restrict__ blkhist, const int* __restrict__ btot,
    int* __restrict__ bstore, int E, int nb, int nblk,
    const float* __restrict__ A, const unsigned short* __restrict__ Wth,
    const unsigned short* __restrict__ Wtl, const float* __restrict__ a_src,
    const float* __restrict__ a_dst, unsigned short* __restrict__ xph,
    float* __restrict__ als, float* __restrict__ ald, int nrows) {
  if ((int)blockIdx.x >= nblk) {
    gemm_body(A, Wth, Wtl, a_src, a_dst, xph, als, ald, nrows, blockIdx.x - nblk);
    return;
  }
  __shared__ int sd[256];
  __shared__ int bb[512];
  __shared__ int cur[512];
  int t = threadIdx.x, blk = blockIdx.x;
  int v0 = (2 * t < nb) ? btot[2 * t] : 0;
  int v1 = (2 * t + 1 < nb) ? btot[2 * t + 1] : 0;
  int s = v0 + v1;
  sd[t] = s;
  __syncthreads();
  for (int off = 1; off < 256; off <<= 1) {
    int add = (t >= off) ? sd[t - off] : 0;
    __syncthreads();
    sd[t] += add;
    __syncthreads();
  }
  int run = sd[t] - s;
  if (2 * t < nb) bb[2 * t] = run;
  if (2 * t + 1 < nb) bb[2 * t + 1] = run + v0;
  __syncthreads();
  for (int i = t; i < nb; i += 256)
    cur[i] = bb[i] + blkhist[(size_t)i * nblk + blk];
  __syncthreads();
  int t0 = blk * TILE;
  int end = t0 + TILE < E ? t0 + TILE : E;
  for (int i = t0 + t; i < end; i += 256) {
    int d = dst[i];
    int pos = atomicAdd(&cur[d >> 7], 1);  // LDS atomic, block-local
    bstore[pos] = ((d & 127) << 16) | src[i];
  }
}

// ---------------- pass 4: per-bucket local CSR (one block per 128-node bucket) ----------------
__global__ __launch_bounds__(256) void k_build(
    const int* __restrict__ bstore, const int* __restrict__ btot,
    int* __restrict__ ssrc, int* __restrict__ deg, int* __restrict__ rstart, int N) {
  __shared__ int ls[BCAP];
  __shared__ unsigned char lloc[BCAP];
  __shared__ int lout[BCAP];
  __shared__ int hist[128];
  __shared__ int sc[128];
  __shared__ int lcur[128];
  __shared__ int red[256];
  int b = blockIdx.x;
  int t = threadIdx.x;
  int pacc = 0;
  for (int j = t; j < b; j += 256) pacc += btot[j];
  red[t] = pacc;
  __syncthreads();
  for (int off = 128; off; off >>= 1) {
    if (t < off) red[t] += red[t + off];
    __syncthreads();
  }
  int base = red[0];
  int cnt = btot[b];
  if (cnt > BCAP) cnt = BCAP;
  int nlo = b << 7;
  if (t < 128) { hist[t] = 0; lcur[t] = 0; }
  __syncthreads();
  for (int i = t; i < cnt; i += 256) {
    int e = bstore[base + i];
    int loc = e >> 16;
    ls[i] = e & 0xffff;
    lloc[i] = (unsigned char)loc;
    atomicAdd(&hist[loc], 1);
  }
  __syncthreads();
  int hv = (t < 128) ? hist[t] : 0;
  if (t < 128) sc[t] = hv;
  __syncthreads();
  for (int off = 1; off < 128; off <<= 1) {
    int add = (t < 128 && t >= off) ? sc[t - off] : 0;
    __syncthreads();
    if (t < 128) sc[t] += add;
    __syncthreads();
  }
  int lstart = (t < 128) ? sc[t] - hv : 0;  // exclusive
  if (t < 128) sc[t] = lstart;
  if (t < 128 && nlo + t < N) {
    deg[nlo + t] = hv;
    rstart[nlo + t] = base + lstart;
  }
  __syncthreads();
  for (int i = t; i < cnt; i += 256) {
    int loc = lloc[i];
    int slot = sc[loc] + atomicAdd(&lcur[loc], 1);
    lout[slot] = ls[i];
  }
  __syncthreads();
  for (int i = t; i < cnt; i += 256) ssrc[base + i] = lout[i];
}

// ---------------- layer-2 GEMM (standalone) ----------------
__global__ __launch_bounds__(256, 2) void k_gemm_mfma(
    const float* __restrict__ A, const unsigned short* __restrict__ Wth,
    const unsigned short* __restrict__ Wtl, const float* __restrict__ a_src,
    const float* __restrict__ a_dst, unsigned short* __restrict__ xph,
    float* __restrict__ als, float* __restrict__ ald, int nrows) {
  gemm_body(A, Wth, Wtl, a_src, a_dst, xph, als, ald, nrows, blockIdx.x);
}

// ---------------- per-node softmax + aggregation (one wave per node, r6 proven) ----------------
__global__ __launch_bounds__(256) void k_aggregate(
    const unsigned short* __restrict__ xph, const float* __restrict__ als,
    const float* __restrict__ ald, const int* __restrict__ rstart,
    const int* __restrict__ deg, const int* __restrict__ ssrc,
    const float* __restrict__ bias, float* __restrict__ out, int N) {
  __shared__ float pbuf[4][128 * 4];  // [wave][edge*4 + head] unnormalized p
  __shared__ int snbuf[4][128];       // [wave][edge] source node
  int wv = threadIdx.x >> 6;
  int lane = threadIdx.x & 63;
  int n = (blockIdx.x * blockDim.x + threadIdx.x) >> 6;
  if (n >= N) return;
  int start = rstart[n];
  int d = deg[n];
  float4 adv = *(const float4*)(ald + (size_t)n * 4);

  // ---- phase A ----
  float m0, m1, m2, m3;
  float s0 = 0.f, s1 = 0.f, s2 = 0.f, s3 = 0.f;
  if (d <= 64) {
    int i = lane;
    bool valid = i < d;
    int sn = valid ? ssrc[start + i] : 0;
    if (valid) snbuf[wv][i] = sn;
    float4 av = *(const float4*)(als + (size_t)sn * 4);
    float L0 = valid ? leaky(av.x + adv.x) : -INFINITY;
    float L1 = valid ? leaky(av.y + adv.y) : -INFINITY;
    float L2 = valid ? leaky(av.z + adv.z) : -INFINITY;
    float L3 = valid ? leaky(av.w + adv.w) : -INFINITY;
    m0 = wmax64(L0); m1 = wmax64(L1); m2 = wmax64(L2); m3 = wmax64(L3);
    float p0 = __expf(L0 - m0);  // invalid lanes: exp(-inf) = 0
    float p1 = __expf(L1 - m1);
    float p2 = __expf(L2 - m2);
    float p3 = __expf(L3 - m3);
    *(float4*)&pbuf[wv][lane * 4] = make_float4(p0, p1, p2, p3);
    s0 = wsum64(p0); s1 = wsum64(p1); s2 = wsum64(p2); s3 = wsum64(p3);
  } else {
    m0 = m1 = m2 = m3 = -INFINITY;
    for (int base = 0; base < d; base += 64) {
      int i = base + lane;
      bool valid = i < d;
      int sn = valid ? ssrc[start + i] : 0;
      if (valid) snbuf[wv][i] = sn;
      float4 av = *(const float4*)(als + (size_t)sn * 4);
      float L0 = valid ? leaky(av.x + adv.x) : -INFINITY;
      float L1 = valid ? leaky(av.y + adv.y) : -INFINITY;
      float L2 = valid ? leaky(av.z + adv.z) : -INFINITY;
      float L3 = valid ? leaky(av.w + adv.w) : -INFINITY;
      if (valid) *(float4*)&pbuf[wv][i * 4] = make_float4(L0, L1, L2, L3);
      m0 = fmaxf(m0, wmax64(L0)); m1 = fmaxf(m1, wmax64(L1));
      m2 = fmaxf(m2, wmax64(L2)); m3 = fmaxf(m3, wmax64(L3));
    }
    for (int base = 0; base < d; base += 64) {
      int i = base + lane;
      bool valid = i < d;
      float4 lv = valid ? *(const float4*)&pbuf[wv][i * 4]
                        : make_float4(-INFINITY, -INFINITY, -INFINITY, -INFINITY);
      float p0 = __expf(lv.x - m0), p1 = __expf(lv.y - m1);
      float p2 = __expf(lv.z - m2), p3 = __expf(lv.w - m3);
      if (valid) *(float4*)&pbuf[wv][i * 4] = make_float4(p0, p1, p2, p3);
      s0 += wsum64(p0); s1 += wsum64(p1); s2 += wsum64(p2); s3 += wsum64(p3);
    }
  }

  // ---- phase B: 4-edge-parallel bf16 gather-accumulate ----
  int cg = lane & 15;   // channel group: channels cg*8 .. cg*8+7
  int es = lane >> 4;   // edge slot 0..3
  int c0 = cg * 8;
  int h = cg >> 2;      // head of my channels
  float a[8] = {0.f, 0.f, 0.f, 0.f, 0.f, 0.f, 0.f, 0.f};
#pragma unroll 2
  for (int t = es; t < d; t += 4) {
    int sn = snbuf[wv][t];
    float p = pbuf[wv][t * 4 + h];
    uint4 rv = *(const uint4*)(xph + (size_t)sn * 128 + c0);
    acc8(a, p, rv);
  }
#pragma unroll
  for (int off = 16; off <= 32; off <<= 1) {
#pragma unroll
    for (int j = 0; j < 8; ++j) a[j] += __shfl_xor(a[j], off);
  }
  if (es == 0) {
    float sden = h == 0 ? s0 : h == 1 ? s1 : h == 2 ? s2 : s3;
    float inv = 1.f / (sden + 1e-16f);
    float4 bv0 = *(const float4*)(bias + c0);
    float4 bv1 = *(const float4*)(bias + c0 + 4);
    float4 o0, o1;
    o0.x = fmaxf(a[0] * inv + bv0.x, 0.f);
    o0.y = fmaxf(a[1] * inv + bv0.y, 0.f);
    o0.z = fmaxf(a[2] * inv + bv0.z, 0.f);
    o0.w = fmaxf(a[3] * inv + bv0.w, 0.f);
    o1.x = fmaxf(a[4] * inv + bv1.x, 0.f);
    o1.y = fmaxf(a[5] * inv + bv1.y, 0.f);
    o1.z = fmaxf(a[6] * inv + bv1.z, 0.f);
    o1.w = fmaxf(a[7] * inv + bv1.w, 0.f);
    *(float4*)(out + (size_t)n * 128 + c0) = o0;
    *(float4*)(out + (size_t)n * 128 + c0 + 4) = o1;
  }
}

extern "C" void kernel_launch(void* const* d_in, const int* in_sizes, int n_in,
                              void* d_out, int out_size, void* d_ws, size_t ws_size,
                              hipStream_t stream) {
  const float* x   = (const float*)d_in[0];
  const int*   src = (const int*)d_in[1];
  const int*   dst = (const int*)d_in[2];
  const float* W0  = (const float*)d_in[3];
  const float* as0 = (const float*)d_in[4];
  const float* ad0 = (const float*)d_in[5];
  const float* b0  = (const float*)d_in[6];
  const float* W1  = (const float*)d_in[7];
  const float* as1 = (const float*)d_in[8];
  const float* ad1 = (const float*)d_in[9];
  const float* b1  = (const float*)d_in[10];
  float* out = (float*)d_out;

  int N = in_sizes[0] / 128;
  int E = in_sizes[1];
  int NB = (N + 127) >> 7;          // buckets of 128 nodes (391)
  int NBLK = (E + TILE - 1) / TILE; // hist/scatter blocks (104, must be <=256)

  char* w = (char*)d_ws;
  auto alloc = [&](size_t bytes) {
    char* p = w;
    w += (bytes + 255) & ~(size_t)255;
    return p;
  };
  int* deg     = (int*)alloc((size_t)N * 4);
  int* rstart  = (int*)alloc((size_t)N * 4);
  int* blkhist = (int*)alloc((size_t)NB * NBLK * 4);
  int* btot    = (int*)alloc((size_t)NB * 4);
  int* bstore  = (int*)alloc((size_t)E * 4);
  int* ssrc    = (int*)alloc((size_t)E * 4);
  unsigned short* xph = (unsigned short*)alloc((size_t)N * 128 * 2);
  float* hbuf  = (float*)alloc((size_t)N * 128 * 4);
  float* als   = (float*)alloc((size_t)N * 4 * 4);
  float* ald   = (float*)alloc((size_t)N * 4 * 4);
  unsigned short* Wth0 = (unsigned short*)alloc(16384 * 2);
  unsigned short* Wtl0 = (unsigned short*)alloc(16384 * 2);
  unsigned short* Wth1 = (unsigned short*)alloc(16384 * 2);
  unsigned short* Wtl1 = (unsigned short*)alloc(16384 * 2);

  int gb = (N + 63) / 64;

  // k1: W split (blocks 0..127) + per-block dst histograms (blocks 128..)
  k_hist_wsplit<<<128 + NBLK, 256, 0, stream>>>(dst, blkhist, E, NB, NBLK,
                                                W0, W1, Wth0, Wtl0, Wth1, Wtl1);
  // k2: per-bucket exclusive scan over blocks
  k_bofs<<<NB, 256, 0, stream>>>(blkhist, btot, NBLK);
  // k3: scatter (blocks 0..NBLK-1) + layer-1 GEMM (blocks NBLK..) — independent work
  k_scatter2_gemm<<<NBLK + gb, 256, 0, stream>>>(
      src, dst, blkhist, btot, bstore, E, NB, NBLK,
      x, Wth0, Wtl0, as0, ad0, xph, als, ald, N);
  // k4: per-bucket local CSR
  k_build<<<NB, 256, 0, stream>>>(bstore, btot, ssrc, deg, rstart, N);
  // k5: layer-1 aggregate
  k_aggregate<<<(N + 3) / 4, 256, 0, stream>>>(xph, als, ald, rstart, deg, ssrc, b0, hbuf, N);
  // k6: layer-2 GEMM
  k_gemm_mfma<<<gb, 256, 0, stream>>>(hbuf, Wth1, Wtl1, as1, ad1, xph, als, ald, N);
  // k7: layer-2 aggregate
  k_aggregate<<<(N + 3) / 4, 256, 0, stream>>>(xph, als, ald, rstart, deg, ssrc, b1, out, N);
}